// Round 14
// baseline (152.978 us; speedup 1.0000x reference)
//
#include <hip/hip_runtime.h>

#define NB 32
#define NI 2048
#define NP 16
#define NJ 32
#define ND 32
#define EPSF 1e-7f

typedef __attribute__((ext_vector_type(8))) short bf16x8;
typedef __attribute__((ext_vector_type(16))) float f32x16;
typedef __attribute__((ext_vector_type(4))) float f32x4;

static __device__ __forceinline__ unsigned cvt_pk_bf16(float lo, float hi) {
  unsigned r;
  asm("v_cvt_pk_bf16_f32 %0, %1, %2" : "=v"(r) : "v"(lo), "v"(hi));
  return r;
}

static __device__ __forceinline__ f32x16 mfma_bf16(bf16x8 a, bf16x8 b, f32x16 c) {
  return __builtin_amdgcn_mfma_f32_32x32x16_bf16(a, b, c, 0, 0, 0);
}

static __device__ __forceinline__ float nt_load(const float* p) {
  return __builtin_nontemporal_load(p);   // read + evict hint (dead-after-read only)
}

// LDS-only barrier: drains ds_write (lgkmcnt) but leaves vmcnt alone, so
// prefetched global W/X loads stay in flight ACROSS the barrier.
// (__syncthreads emits s_waitcnt vmcnt(0) -> kills the software pipeline.)
// The only inter-wave dependency here is lgt[] in LDS, so lgkmcnt(0) suffices.
static __device__ __forceinline__ void lds_barrier() {
  asm volatile("s_waitcnt lgkmcnt(0)\n\ts_barrier" ::: "memory");
}

// Raw W row gather for one (i,j): 8 f32 at stride ND. Loads issue HERE;
// conversion happens at use (pack_wfrag) so prefetched loads overlap compute.
struct wraw { float f[8]; };
static __device__ __forceinline__ wraw load_wraw(const float* __restrict__ W,
                                                 int i, int j, int h, int d) {
  const float* wp = W + (((size_t)i * NJ + j) * NP + h * 8) * ND + d;
  wraw r;
#pragma unroll
  for (int e = 0; e < 8; ++e) r.f[e] = wp[e * ND];
  return r;
}
// A operand: lane l: m = d = l&31, k = p = 8*(l>>5) + e
static __device__ __forceinline__ bf16x8 pack_wfrag(const wraw& r) {
  union { unsigned u[4]; bf16x8 v; } wf;
  wf.u[0] = cvt_pk_bf16(r.f[0], r.f[1]);
  wf.u[1] = cvt_pk_bf16(r.f[2], r.f[3]);
  wf.u[2] = cvt_pk_bf16(r.f[4], r.f[5]);
  wf.u[3] = cvt_pk_bf16(r.f[6], r.f[7]);
  return wf.v;
}

// B operand: lane l: k = p = 8*(l>>5)+e, n = b = l&31
static __device__ __forceinline__ bf16x8 load_xfrag(const unsigned short* __restrict__ Xt,
                                                    int i, int b, int h) {
  return *(const bf16x8*)(Xt + ((size_t)i * NB + b) * NP + h * 8);
}

// ---------- prep: inputs[b][i][p] (f32) -> Xt[i][b][p] (bf16) ----------
__global__ __launch_bounds__(256) void kern_prep(const float* __restrict__ in,
                                                 unsigned short* __restrict__ Xt) {
  const int t = blockIdx.x * 256 + threadIdx.x;   // 262144 threads, 4 elems each
  const int rest = t >> 2;                        // b*NI + i
  const int p4 = (t & 3) * 4;
  const int i = rest & (NI - 1);
  const int b = rest >> 11;
  f32x4 x = *(const f32x4*)(in + (size_t)rest * NP + p4);
  uint2 v;
  v.x = cvt_pk_bf16(x[0], x[1]);
  v.y = cvt_pk_bf16(x[2], x[3]);
  *(uint2*)(Xt + ((size_t)i * NB + b) * NP + p4) = v;
}

// ---------- fused routing pass over an i-chunk ----------
// 512 threads = 8 waves; wave w owns j = w*4 + t (t=0..3); block ch covers ipb i's.
// R14: the two __syncthreads() in the routing path are replaced by lds_barrier()
// (lgkmcnt-only). R13's prefetch was being DRAINED by __syncthreads' implicit
// vmcnt(0); now the next-iteration W/X loads span the whole iteration (~full
// HBM-latency cover). sacc stays pure-MFMA C/D (AGPR); softmax c applied by
// re-MFMA with c-scaled B operand (proven R12/R13 numerics, absmax 0.0039).
template <bool UNIFORM>
__global__ __attribute__((amdgpu_waves_per_eu(2, 2)))
__launch_bounds__(512) void kern_fused(const float* __restrict__ W,
                                       const unsigned short* __restrict__ Xt,
                                       const float* __restrict__ vsum,
                                       float* __restrict__ part,
                                       int ipb, int nch) {
  const int tid = threadIdx.x;
  const int w = tid >> 6;
  const int lane = tid & 63;
  const int b = lane & 31;
  const int h = lane >> 5;
  const int ch = blockIdx.x;
  const int i0 = ch * ipb;

  // register-resident vsum fragment: vs[t][q][e] = vsum[b][j=w*4+t][8q + 4h + e]
  f32x4 vs[4][4];
  if (!UNIFORM) {
#pragma unroll
    for (int t = 0; t < 4; ++t) {
      const int j = w * 4 + t;
#pragma unroll
      for (int q = 0; q < 4; ++q)
        vs[t][q] = *(const f32x4*)(vsum + ((size_t)b * NJ + j) * ND + q * 8 + h * 4);
    }
  }

  f32x16 sacc[4] = {};
  __shared__ float lgt[NJ][33];

  // pipeline prologue: loads for ii = 0
  wraw wr[4];
  bf16x8 xf;
#pragma unroll
  for (int t = 0; t < 4; ++t) wr[t] = load_wraw(W, i0, w * 4 + t, h, b);
  xf = load_xfrag(Xt, i0, b, h);

  for (int ii = 0; ii < ipb; ++ii) {
    const int i = i0 + ii;
    // issue next iteration's loads NOW; with lds_barrier they stay in flight
    // across BOTH barriers and land by next iteration's pack_wfrag.
    const int inext = (ii + 1 < ipb) ? i + 1 : i;   // clamped: harmless re-read
    wraw wrn[4];
#pragma unroll
    for (int t = 0; t < 4; ++t) wrn[t] = load_wraw(W, inext, w * 4 + t, h, b);
    const bf16x8 xfn = load_xfrag(Xt, inext, b, h);

    // convert current W to bf16 fragments
    bf16x8 wf[4];
#pragma unroll
    for (int t = 0; t < 4; ++t) wf[t] = pack_wfrag(wr[t]);

    if (UNIFORM) {
#pragma unroll
      for (int t = 0; t < 4; ++t) sacc[t] = mfma_bf16(wf[t], xf, sacc[t]);
    } else {
      // unpack this lane's 8 bf16 x-values to f32 (for the c-scaled re-pack)
      union { bf16x8 v; unsigned short s[8]; } xu; xu.v = xf;
      float xf32[8];
#pragma unroll
      for (int e = 0; e < 8; ++e)
        xf32[e] = __uint_as_float((unsigned)xu.s[e] << 16);

      float lg[4];
#pragma unroll
      for (int t = 0; t < 4; ++t) {
        f32x16 z = {};
        const f32x16 um = mfma_bf16(wf[t], xf, z);   // transient: dies before barrier
        float p = 0.f;
#pragma unroll
        for (int r = 0; r < 16; ++r)
          p += um[r] * vs[t][r >> 2][r & 3];         // d(r) = (r&3) + 8*(r>>2) + 4h
        p += __shfl_xor(p, 32);                      // add partner half's 16 d's
        lg[t] = p;
      }
      if (h == 0) {
#pragma unroll
        for (int t = 0; t < 4; ++t) lgt[w * 4 + t][b] = lg[t];
      }
      lds_barrier();                                 // lgkmcnt-only: vmcnt untouched
      // per-(b,i) softmax over j (each thread reduces its own b's column)
      float mx = -3.0e38f;
#pragma unroll
      for (int jj = 0; jj < NJ; ++jj) mx = fmaxf(mx, lgt[jj][b]);
      float den = 0.f;
#pragma unroll
      for (int jj = 0; jj < NJ; ++jj) den += expf(lgt[jj][b] - mx);
      const float inv = 1.0f / den;
#pragma unroll
      for (int t = 0; t < 4; ++t) {
        const float c = expf(lg[t] - mx) * inv;
        union { unsigned u[4]; bf16x8 v; } xc;
#pragma unroll
        for (int e = 0; e < 4; ++e)
          xc.u[e] = cvt_pk_bf16(xf32[2 * e] * c, xf32[2 * e + 1] * c);
        sacc[t] = mfma_bf16(wf[t], xc.v, sacc[t]);   // sacc stays pure-MFMA
      }
      lds_barrier();   // protect lgt before next i overwrites it (vmcnt untouched)
    }

    // rotate pipeline registers
#pragma unroll
    for (int t = 0; t < 4; ++t) wr[t] = wrn[t];
    xf = xfn;
  }

  // epilogue: 4 contiguous f32x4 stores per (t) instead of 16 scattered dwords.
#pragma unroll
  for (int t = 0; t < 4; ++t) {
    const int j = w * 4 + t;
    float* base = &part[(((size_t)j * nch + ch) * NB + b) * ND];
#pragma unroll
    for (int rq = 0; rq < 4; ++rq) {
      f32x4 v4;
#pragma unroll
      for (int e = 0; e < 4; ++e) {
        const float val = UNIFORM ? sacc[t][rq * 4 + e] * (1.0f / 32.0f)
                                  : sacc[t][rq * 4 + e];
        v4[e] = val;
      }
      *(f32x4*)(base + rq * 8 + 4 * h) = v4;   // d = 8*rq + 4h + e
    }
  }
}

// ---------- stage-1 reduce: 32-chunk groups -> part2[j][r][b][d] ----------
// nt_load: part is dead after this read -> evict-hint frees L2/L3 for W.
__global__ __launch_bounds__(1024) void kern_reduce1(const float* __restrict__ part,
                                                     float* __restrict__ part2,
                                                     int nch, int RG) {
  const int j = blockIdx.x / RG;
  const int r = blockIdx.x % RG;
  const int t = threadIdx.x;
  const int b = t >> 5;
  const int d = t & 31;
  float s = 0.f;
#pragma unroll 4
  for (int c = 0; c < 32; ++c)
    s += nt_load(&part[(((size_t)j * nch + r * 32 + c) * NB + b) * ND + d]);
  part2[(((size_t)j * RG + r) * NB + b) * ND + d] = s;
}

// ---------- final reduce + squash + vsum/out ----------
__global__ __launch_bounds__(1024) void kern_squash(const float* __restrict__ part2,
                                                    float* __restrict__ vsum,
                                                    float* __restrict__ out,
                                                    int mode, int RG) {
  const int j = blockIdx.x;
  const int t = threadIdx.x;
  const int b = t >> 5;
  const int d = t & 31;
  float s = 0.f;
  for (int r = 0; r < RG; ++r)
    s += nt_load(&part2[(((size_t)j * RG + r) * NB + b) * ND + d]);

  __shared__ float sl[32][33];
  __shared__ float fb[32];
  sl[b][d] = s;
  __syncthreads();
  if (t < 32) {
    float n2 = 0.f;
#pragma unroll
    for (int dd = 0; dd < ND; ++dd) { const float x = sl[t][dd]; n2 += x * x; }
    fb[t] = n2 / ((1.0f + n2) * sqrtf(n2 + EPSF));
  }
  __syncthreads();
  const float v = s * fb[b];
  const int idx = (b * NJ + j) * ND + d;
  if (mode == 0)      vsum[idx] = v;        // iter0: vsum := v0 (never read-before-write)
  else if (mode == 1) vsum[idx] += v;       // iter1: vsum := v0+v1
  else                out[idx] = v;         // iter2: final output [B,J,D]
}

extern "C" void kernel_launch(void* const* d_in, const int* in_sizes, int n_in,
                              void* d_out, int out_size, void* d_ws, size_t ws_size,
                              hipStream_t stream) {
  const float* inp = (const float*)d_in[0];
  const float* W   = (const float*)d_in[1];
  // defensive: inputs is 1M elems, W is 33.5M elems
  if (n_in >= 2 && in_sizes[0] > in_sizes[1]) { const float* tmp = inp; inp = W; W = tmp; }
  float* out = (float*)d_out;
  char* ws = (char*)d_ws;
  (void)out_size;

  // proven layout: Xt@0 (2MB) | part (nch*128KB) | vsum (128KB) | part2 (RG*128KB)
  int nch = 256;
  while (nch > 32 &&
         (size_t)(2u << 20) + (size_t)nch * 131072u + 131072u +
             (size_t)(nch / 32) * 131072u > ws_size)
    nch >>= 1;
  const int ipb = NI / nch;
  const int RG = nch / 32;

  unsigned short* Xt = (unsigned short*)ws;
  float* part  = (float*)(ws + (2u << 20));
  float* vsum  = part + (size_t)NJ * nch * NB * ND;   // full part extent
  float* part2 = vsum + (size_t)NB * NJ * ND;         // after vsum

  kern_prep<<<1024, 256, 0, stream>>>(inp, Xt);

  // iter 0: uniform c = 1/32
  kern_fused<true><<<nch, 512, 0, stream>>>(W, Xt, nullptr, part, ipb, nch);
  kern_reduce1<<<32 * RG, 1024, 0, stream>>>(part, part2, nch, RG);
  kern_squash<<<32, 1024, 0, stream>>>(part2, vsum, out, 0, RG);

  // iter 1
  kern_fused<false><<<nch, 512, 0, stream>>>(W, Xt, vsum, part, ipb, nch);
  kern_reduce1<<<32 * RG, 1024, 0, stream>>>(part, part2, nch, RG);
  kern_squash<<<32, 1024, 0, stream>>>(part2, vsum, out, 1, RG);

  // iter 2
  kern_fused<false><<<nch, 512, 0, stream>>>(W, Xt, vsum, part, ipb, nch);
  kern_reduce1<<<32 * RG, 1024, 0, stream>>>(part, part2, nch, RG);
  kern_squash<<<32, 1024, 0, stream>>>(part2, vsum, out, 2, RG);
}